// Round 5
// baseline (132.176 us; speedup 1.0000x reference)
//
#include <hip/hip_runtime.h>
#include <math.h>

// Problem constants
#define BATCH 8192
#define NFEAT 256
#define NH1   100     // fc1 width (K of fc2)
#define NH2   50      // fc2 width (N of fc2)
#define KP    128     // K padded: 4 MFMA k-steps of 32
#define FPB   8       // features per block (inner loop)
#define RPB   256     // batch rows per block (32 per wave, 8 waves)

typedef __attribute__((ext_vector_type(8))) _Float16 half8;   // MFMA A/B frag
typedef __attribute__((ext_vector_type(2))) _Float16 h2v;     // packed fp16 pair
typedef __attribute__((ext_vector_type(4))) float    float4v; // MFMA acc

// ---- workspace layout (fp32 units from ws start) ----
// w2h : NFEAT*8192 f16 = 4 MB (fragment-ordered, zero-padded)
// w1h/b1h : NFEAT*KP f16 (zero-padded); tkt: 32 u32 row-block tickets
#define OFF_W1H  (NFEAT * 8192 / 2)
#define OFF_B1H  (OFF_W1H + NFEAT * KP / 2)
#define OFF_TKT  (OFF_B1H + NFEAT * KP / 2)

// ---- prep v3 (R26): one block per feature, 512 thr. Full W2 row staged
// once (50 x 104-pad f32, 20.8 KB), fragment emit as paired-f16 u32 stores.
// vs v2: 1/4 the blocks, 1/2 the kernel-wide LDS loads, 2x wider stores.
// Also: w1/b1 cvt, out zeroing, finish-ticket zeroing — all in one dispatch.
__global__ __launch_bounds__(512) void prep(
    const float* __restrict__ W1, const float* __restrict__ b1,
    const float* __restrict__ W2, float* __restrict__ ws,
    float* __restrict__ out)
{
    __shared__ float l2[NH2 * 104];      // 20.8 KB
    const int f = blockIdx.x;
    const int t = threadIdx.x;

    // w1h/b1h slices + out zero + ticket zero (independent of l2)
    if (t < KP) {
        _Float16* w1h = (_Float16*)(ws + OFF_W1H) + f * KP;
        w1h[t] = (_Float16)((t < NH1) ? W1[f * NH1 + t] : 0.f);
    } else if (t < 2 * KP) {
        _Float16* b1h = (_Float16*)(ws + OFF_B1H) + f * KP;
        const int k = t - KP;
        b1h[k] = (_Float16)((k < NH1) ? b1[f * NH1 + k] : 0.f);
    } else if (t < 2 * KP + 32) {
        out[f * 32 + (t - 2 * KP)] = 0.f;
    } else if (t == 2 * KP + 32 && f < 32) {
        ((unsigned*)(ws + OFF_TKT))[f] = 0u;
    }

    // stage full W2[f] (50x100) coalesced -> LDS (stride 104)
    const float* __restrict__ w2g = W2 + (size_t)f * NH2 * NH1;
    for (int idx = t; idx < NH2 * NH1; idx += 512)
        l2[(idx / NH1) * 104 + (idx % NH1)] = w2g[idx];
    __syncthreads();

    // fragment emit: 8192 f16 per feature as 4096 u32 (2 f16 each).
    // within-feature el: q=el>>11, nt=(el>>9)&3, lane=(el>>3)&63, j=el&7;
    // o = nt*16 + (lane&15), h = q*32 + (lane>>4)*8 + j. Pairs share all
    // fields except j (even/odd) -> one u32 store per pair.
    h2v* dst = (h2v*)((_Float16*)ws + (size_t)f * 8192);
#pragma unroll
    for (int i = 0; i < 8; ++i) {
        const int p    = i * 512 + t;        // u32 index 0..4095
        const int el   = p * 2;
        const int q    = el >> 11;
        const int nt   = (el >> 9) & 3;
        const int lane = (el >> 3) & 63;
        const int j    = el & 7;             // even
        const int o    = nt * 16 + (lane & 15);
        const int h    = q * 32 + ((lane >> 4) << 3) + j;
        float v0 = 0.f, v1 = 0.f;
        if (o < NH2) {
            v0 = (h     < NH1) ? l2[o * 104 + h]     : 0.f;
            v1 = (h + 1 < NH1) ? l2[o * 104 + h + 1] : 0.f;
        }
        dst[p] = (h2v){(_Float16)v0, (_Float16)v1};
    }
}

// async 16KB stage for 512-thread block: 2 x (512 lanes x 16B) DMA.
__device__ __forceinline__ void stage_async(
    const _Float16* __restrict__ src, _Float16* dst, int t)
{
#pragma unroll
    for (int i = 0; i < 2; ++i) {
        const _Float16* g = src + (i * 512 + t) * 8;
        _Float16* l       = dst + (i * 512 + t) * 8;
        __builtin_amdgcn_global_load_lds(
            (const __attribute__((address_space(1))) unsigned*)g,
            (__attribute__((address_space(3))) unsigned*)l, 16, 0, 0);
    }
}

// ---- main, R26: R22 body restored (proven 45.5us local optimum) + fused
// sigmoid finish via row-block ticket. R23-R25 post-mortems: MFMA busy is
// constant ~13.5us; duration tracks VALU + dependency stalls, not LDS
// traffic (R25 cut LDS 30->21us/CU but duplicated A-build VALU -> lost).
// R22's mt=2 x nt=4 is VALU-minimal (A-build once per (row,k)). Kept
// micro-opts: b2 folded into acc C-in, b2/W3 hoisted to iter top.
// Ticket finish: __syncthreads drains all waves' atomics; last of the 32
// by-blocks per row-block fences + applies sigmoid. Removes nam_finish
// dispatch + its launch gap.
__global__ __launch_bounds__(512, 4) void nam_mfma(
    const float* __restrict__ x,
    const float* __restrict__ ws,
    const float* __restrict__ b2,
    const float* __restrict__ W3,
    const float* __restrict__ bias,
    float* __restrict__ out)
{
    __shared__ _Float16 lds[2][8192];      // 32 KB: B-fragment double buffer
    __shared__ _Float16 xshh[FPB * RPB];   // 4 KB: x[fi][row] fp16 (transposed)
    __shared__ _Float16 wsh[FPB * KP];     // 2 KB: W1 slices
    __shared__ _Float16 csh[FPB * KP];     // 2 KB: b1 slices
    __shared__ unsigned last_flag;

    const int t   = threadIdx.x;
    const int wv  = t >> 6;                // wave 0..7
    const int l64 = t & 63;
    const int ln  = t & 15;
    const int qd  = (t >> 4) & 3;
    const int rowbase = blockIdx.x * RPB + wv * 32;
    const int f0      = blockIdx.y * FPB;

    const _Float16* w2h = (const _Float16*)ws;
    const _Float16* w1h = (const _Float16*)(ws + OFF_W1H);
    const _Float16* b1h = (const _Float16*)(ws + OFF_B1H);

    int osrc[4];
#pragma unroll
    for (int nt = 0; nt < 4; ++nt) {
        const int o = nt * 16 + ln;
        osrc[nt] = (o < NH2) ? o : 0;      // clamped; killed by wo=0
    }

    // ---- one-time staging: B f0 (async) + x tile (fp16 transposed) + w1/b1
    stage_async(w2h + (size_t)f0 * 8192, lds[0], t);
    {
        const int r = t >> 1, half = t & 1;           // 512 thr: 256 rows x 2
        const float4 v = *(const float4*)(
            x + (size_t)(blockIdx.x * RPB + r) * NFEAT + f0 + half * 4);
        xshh[(half * 4 + 0) * RPB + r] = (_Float16)v.x;
        xshh[(half * 4 + 1) * RPB + r] = (_Float16)v.y;
        xshh[(half * 4 + 2) * RPB + r] = (_Float16)v.z;
        xshh[(half * 4 + 3) * RPB + r] = (_Float16)v.w;
    }
    if (t < 128)
        ((int4*)wsh)[t] = ((const int4*)(w1h + (size_t)f0 * KP))[t];
    else if (t < 256)
        ((int4*)csh)[t - 128] = ((const int4*)(b1h + (size_t)f0 * KP))[t - 128];
    __syncthreads();

    float rp[2][4] = {{0.f}, {0.f}};       // contrib, summed over f

#pragma unroll 1
    for (int fi = 0; fi < FPB; ++fi) {
        const int f = f0 + fi;
        const _Float16* B = lds[fi & 1];

        // DMA f+1 into the other buffer; lands by this iter's end barrier
        if (fi + 1 < FPB)
            stage_async(w2h + (size_t)(f + 1) * 8192, lds[(fi + 1) & 1], t);

        // per-feature b2/W3 -> regs (L1 broadcast loads, whole iter of slack)
        const float* __restrict__ b2g = b2 + f * NH2;
        const float* __restrict__ w3g = W3 + f * NH2;
        float bo[4], wo[4];
#pragma unroll
        for (int nt = 0; nt < 4; ++nt) {
            const int o = nt * 16 + ln;
            bo[nt] = b2g[osrc[nt]];
            wo[nt] = (o < NH2) ? w3g[osrc[nt]] : 0.f;
        }

        // x from LDS: consecutive halfwords, broadcast across quads
        h2v xh[2];
#pragma unroll
        for (int mt = 0; mt < 2; ++mt) {
            const _Float16 xs = xshh[fi * RPB + wv * 32 + mt * 16 + ln];
            xh[mt] = (h2v){xs, xs};
        }

        // acc init = b2 (folds the epilogue's +bo add into the MFMA C-in)
        float4v acc[2][4];
#pragma unroll
        for (int mt = 0; mt < 2; ++mt)
#pragma unroll
            for (int nt = 0; nt < 4; ++nt)
                acc[mt][nt] = (float4v){bo[nt], bo[nt], bo[nt], bo[nt]};

        const h2v z2 = (h2v){(_Float16)0.f, (_Float16)0.f};

#pragma unroll
        for (int kk = 0; kk < 4; ++kk) {
            half8 bf[4];
#pragma unroll
            for (int nt = 0; nt < 4; ++nt)
                bf[nt] = *(const half8*)(B + (kk * 4 + nt) * 512 + l64 * 8);

            // w1/b1 fragment: one ds_read_b128 each (contiguous 8 f16)
            const half8 wv8 = *(const half8*)(wsh + fi * KP + kk * 32 + qd * 8);
            const half8 cv8 = *(const half8*)(csh + fi * KP + kk * 32 + qd * 8);
            const h2v* wpp = (const h2v*)&wv8;
            const h2v* cpp = (const h2v*)&cv8;

#pragma unroll
            for (int mt = 0; mt < 2; ++mt) {
                half8 af;
                h2v* ap = (h2v*)&af;
                ap[0] = __builtin_elementwise_max(wpp[0] * xh[mt] + cpp[0], z2);
                ap[1] = __builtin_elementwise_max(wpp[1] * xh[mt] + cpp[1], z2);
                ap[2] = __builtin_elementwise_max(wpp[2] * xh[mt] + cpp[2], z2);
                ap[3] = __builtin_elementwise_max(wpp[3] * xh[mt] + cpp[3], z2);
#pragma unroll
                for (int nt = 0; nt < 4; ++nt)
                    acc[mt][nt] = __builtin_amdgcn_mfma_f32_16x16x32_f16(
                        af, bf[nt], acc[mt][nt], 0, 0, 0);
            }
        }

        // epilogue: h2 = relu(acc) (b2 already inside); rp += h2 * w3
#pragma unroll
        for (int nt = 0; nt < 4; ++nt)
#pragma unroll
            for (int mt = 0; mt < 2; ++mt)
#pragma unroll
                for (int r = 0; r < 4; ++r)
                    rp[mt][r] = fmaf(fmaxf(acc[mt][nt][r], 0.f), wo[nt], rp[mt][r]);

        __syncthreads();   // drains DMA (f+1 ready) + releases buffer fi&1
    }

    // ---- shuffle-reduce rp over the 16 columns, one atomic per row ----
#pragma unroll
    for (int mt = 0; mt < 2; ++mt)
#pragma unroll
        for (int r = 0; r < 4; ++r) {
            float v = rp[mt][r];
            v += __shfl_xor(v, 1);
            v += __shfl_xor(v, 2);
            v += __shfl_xor(v, 4);
            v += __shfl_xor(v, 8);
            if (ln == 0)
                atomicAdd(out + rowbase + mt * 16 + qd * 4 + r, v);
        }

    // ---- fused finish: last of the 32 by-blocks for this row-block applies
    // sigmoid. __syncthreads has release semantics (drains all waves'
    // outstanding atomics before s_barrier), then fence + device-scope ticket.
    __syncthreads();
    if (t == 0) {
        __threadfence();
        unsigned* tkt = (unsigned*)(ws + OFF_TKT);
        const unsigned prev = atomicAdd(tkt + blockIdx.x, 1u);
        last_flag = (prev == (NFEAT / FPB - 1)) ? 1u : 0u;
    }
    __syncthreads();
    if (last_flag) {
        __threadfence();   // acquire side: see all other blocks' adds
        if (t < RPB) {
            const int row = blockIdx.x * RPB + t;
            const float v = out[row] + bias[0];
            out[row] = 1.0f / (1.0f + expf(-v));
        }
    }
}

extern "C" void kernel_launch(void* const* d_in, const int* in_sizes, int n_in,
                              void* d_out, int out_size, void* d_ws, size_t ws_size,
                              hipStream_t stream) {
    const float* x    = (const float*)d_in[0];
    const float* W1   = (const float*)d_in[1];
    const float* b1   = (const float*)d_in[2];
    const float* W2   = (const float*)d_in[3];
    const float* b2   = (const float*)d_in[4];
    const float* W3   = (const float*)d_in[5];
    const float* bias = (const float*)d_in[6];
    float* out = (float*)d_out;
    float* ws  = (float*)d_ws;   // ~4.33 MB used

    prep<<<NFEAT, 512, 0, stream>>>(W1, b1, W2, ws, out);

    nam_mfma<<<dim3(BATCH / RPB, NFEAT / FPB), 512, 0, stream>>>(
        x, ws, b2, W3, bias, out);
}